// Round 6
// baseline (120.945 us; speedup 1.0000x reference)
//
#include <hip/hip_runtime.h>
#include <math.h>

// Lorenz Lyapunov-exponent integrator — round 6.
// R5 post-mortem: packed fp32 never formed, and CDNA4 packed fp32 is 2-pass
// anyway (FP32 peak 157.3 TF = 1 fma/lane/cyc) — instruction count per
// trajectory is invariant to traj/thread. The only knob that moved VALUBusy
// across R1..R5 is waves/SIMD (4->90%, 2->63-73%, 1->66%).
// So: 1 trajectory/thread (262144 threads = 4 waves/SIMD, the max this B
// allows), keeping the R4/R5 algebra: GS every K=20 steps, zero per-step
// transcendentals, telescoped log-norms at the end.
// Issue floor: ~78 VALU insts/step * 2 cyc * 4 waves = 624 cyc/SIMD/step
// -> 26 us at 100% issue; predict 28-31 us at ~90%.

#define SIGMA 10.0f
#define RHO   28.0f
#define DT    0.01f
#define BETA  (8.0f / 3.0f)
#define LN2_HALF 0.34657359027997264f   // 0.5 * ln(2)
#define GS_K 20

#pragma clang fp contract(fast)

__device__ __forceinline__ void lorenz_f(float X, float Y, float Z,
                                         float& fx, float& fy, float& fz) {
    fx = SIGMA * (Y - X);
    fy = X * (RHO - Z) - Y;
    fz = X * Y - BETA * Z;
}

struct State {
    float X, Y, Z;
    float q00, q01, q02, q10, q11, q12, q20, q21, q22;
};

__device__ __forceinline__ void rk4_jq_step(State& s) {
    // ---- RK4 step (reference quirk: k4 uses k2, not k3) ----
    float k1x, k1y, k1z, k2x, k2y, k2z, k3x, k3y, k3z, k4x, k4y, k4z;
    lorenz_f(s.X, s.Y, s.Z, k1x, k1y, k1z);
    lorenz_f(s.X + (DT * 0.5f) * k1x, s.Y + (DT * 0.5f) * k1y, s.Z + (DT * 0.5f) * k1z,
             k2x, k2y, k2z);
    lorenz_f(s.X + (DT * 0.5f) * k2x, s.Y + (DT * 0.5f) * k2y, s.Z + (DT * 0.5f) * k2z,
             k3x, k3y, k3z);
    lorenz_f(s.X + DT * k2x, s.Y + DT * k2y, s.Z + DT * k2z,   // (sic) k2
             k4x, k4y, k4z);
    s.X = s.X + DT * (k1x + 2.0f * k2x + 2.0f * k3x + k4x) * (1.0f / 6.0f);
    s.Y = s.Y + DT * (k1y + 2.0f * k2y + 2.0f * k3y + k4y) * (1.0f / 6.0f);
    s.Z = s.Z + DT * (k1z + 2.0f * k2z + 2.0f * k3z + k4z) * (1.0f / 6.0f);

    // ---- Tangent map J = I + DT*Df at the NEW x (j02 == 0) ----
    const float j10 = DT * (RHO - s.Z);
    const float j12 = -DT * s.X;
    const float j20 = DT * s.Y;
    const float j21 = DT * s.X;
    const float j00 = 1.0f - DT * SIGMA;
    const float j01 = DT * SIGMA;
    const float j11 = 1.0f - DT;
    const float j22 = 1.0f - DT * BETA;

    // ---- Q = J @ Q ----
    float n00 = j00 * s.q00 + j01 * s.q10;
    float n01 = j00 * s.q01 + j01 * s.q11;
    float n02 = j00 * s.q02 + j01 * s.q12;
    float n10 = j10 * s.q00 + j11 * s.q10 + j12 * s.q20;
    float n11 = j10 * s.q01 + j11 * s.q11 + j12 * s.q21;
    float n12 = j10 * s.q02 + j11 * s.q12 + j12 * s.q22;
    float n20 = j20 * s.q00 + j21 * s.q10 + j22 * s.q20;
    float n21 = j20 * s.q01 + j21 * s.q11 + j22 * s.q21;
    float n22 = j20 * s.q02 + j21 * s.q12 + j22 * s.q22;
    s.q00 = n00; s.q01 = n01; s.q02 = n02;
    s.q10 = n10; s.q11 = n11; s.q12 = n12;
    s.q20 = n20; s.q21 = n21; s.q22 = n22;
}

__device__ __forceinline__ void gram_schmidt(State& s) {
    // Classical GS, unnormalized, projection coeffs from ORIGINAL columns.
    float ib0 = s.q00 * s.q00 + s.q10 * s.q10 + s.q20 * s.q20;
    float rib0 = __builtin_amdgcn_rcpf(ib0);

    float d01 = s.q00 * s.q01 + s.q10 * s.q11 + s.q20 * s.q21;
    float c1 = d01 * rib0;
    float b10 = s.q01 - c1 * s.q00;
    float b11 = s.q11 - c1 * s.q10;
    float b12 = s.q21 - c1 * s.q20;

    float d02 = s.q00 * s.q02 + s.q10 * s.q12 + s.q20 * s.q22;
    float c2 = d02 * rib0;
    float e0 = s.q02 - c2 * s.q00;
    float e1 = s.q12 - c2 * s.q10;
    float e2 = s.q22 - c2 * s.q20;
    float ib1 = b10 * b10 + b11 * b11 + b12 * b12;
    float d12 = b10 * s.q02 + b11 * s.q12 + b12 * s.q22;
    float c3 = d12 * __builtin_amdgcn_rcpf(ib1);
    s.q02 = e0 - c3 * b10;
    s.q12 = e1 - c3 * b11;
    s.q22 = e2 - c3 * b12;
    s.q01 = b10; s.q11 = b11; s.q21 = b12;
}

__global__ __launch_bounds__(256, 4)
void lorenz_lya_kernel(const float* __restrict__ x0,
                       const float* __restrict__ ts,
                       float* __restrict__ out,
                       int B, int T) {
    int b = blockIdx.x * blockDim.x + threadIdx.x;
    if (b >= B) return;

    State s;
    s.X = x0[0 * B + b];
    s.Y = x0[1 * B + b];
    s.Z = x0[2 * B + b];
    s.q00 = 1.0f; s.q01 = 0.0f; s.q02 = 0.0f;
    s.q10 = 0.0f; s.q11 = 1.0f; s.q12 = 0.0f;
    s.q20 = 0.0f; s.q21 = 0.0f; s.q22 = 1.0f;

    float t_last = ts[T - 1];

    int it = 0;
    while (it < T) {
        int kend = T - it;
        if (kend >= GS_K) {
            #pragma unroll 5
            for (int u = 0; u < GS_K; ++u) rk4_jq_step(s);
            it += GS_K;
        } else {
            for (int u = 0; u < kend; ++u) rk4_jq_step(s);
            it += kend;
        }
        gram_schmidt(s);
    }

    // Final column norms^2; lya_j = 0.5*ln2*log2(ib_j) / (t_last + DT)
    float ib0 = s.q00 * s.q00 + s.q10 * s.q10 + s.q20 * s.q20;
    float ib1 = s.q01 * s.q01 + s.q11 * s.q11 + s.q21 * s.q21;
    float ib2 = s.q02 * s.q02 + s.q12 * s.q12 + s.q22 * s.q22;

    float scale = LN2_HALF * __builtin_amdgcn_rcpf(t_last + DT);
    out[0 * B + b] = __builtin_amdgcn_logf(ib0) * scale;
    out[1 * B + b] = __builtin_amdgcn_logf(ib1) * scale;
    out[2 * B + b] = __builtin_amdgcn_logf(ib2) * scale;
    out[3 * B + b] = s.X;
    out[4 * B + b] = s.Y;
    out[5 * B + b] = s.Z;
}

extern "C" void kernel_launch(void* const* d_in, const int* in_sizes, int n_in,
                              void* d_out, int out_size, void* d_ws, size_t ws_size,
                              hipStream_t stream) {
    const float* x0 = (const float*)d_in[0];
    const float* ts = (const float*)d_in[1];
    float* out = (float*)d_out;
    int B = in_sizes[0] / 3;
    int T = in_sizes[1];
    int threads = 256;
    int blocks = (B + threads - 1) / threads;
    lorenz_lya_kernel<<<blocks, threads, 0, stream>>>(x0, ts, out, B, T);
}